// Round 11
// baseline (356.641 us; speedup 1.0000x reference)
//
#include <hip/hip_runtime.h>
#include <hip/hip_fp16.h>
#include <math.h>

#define IN_F 50
#define HID 64
#define NC 12
#define LN_EPS 1e-5f

// Bucketed CSR build parameters
#define BSH 8                 // bucket = dst >> 8 (256 nodes/bucket)
#define BSZ 256
#define NBK_MAX 256
#define CHUNK 8192
#define PCAP 8192             // per-bucket capacity (mean 4096, +64 sigma)

#define SCQ 0.36067376022224085f   // 0.25 * log2(e)

typedef _Float16 half8 __attribute__((ext_vector_type(8)));
typedef _Float16 half4_t __attribute__((ext_vector_type(4)));
typedef _Float16 half2_t __attribute__((ext_vector_type(2)));
typedef float float4v __attribute__((ext_vector_type(4)));
typedef unsigned int uint2v __attribute__((ext_vector_type(2)));

static __device__ __forceinline__ half2_t h2cast(unsigned int u) {
  return __builtin_bit_cast(half2_t, u);
}

#if __has_builtin(__builtin_amdgcn_fdot2)
#define FDOT2(a, b, c) __builtin_amdgcn_fdot2((a), (b), (c), false)
#else
static __device__ __forceinline__ float FDOT2(half2_t a, half2_t b, float c) {
  return (float)a[0] * (float)b[0] + (float)a[1] * (float)b[1] + c;
}
#endif

// ---------------- CSR construction (bucketed counting sort) ----------------

__global__ __launch_bounds__(256) void bucket_kernel(
    const int* __restrict__ src, const int* __restrict__ dst,
    const float* __restrict__ ea, int* __restrict__ cursor,
    unsigned long long* __restrict__ rec_stage,
    unsigned short* __restrict__ dloc_stage, int e)
{
  __shared__ int bcnt[256];
  __shared__ int gbase[256];
  __shared__ int bfill[256];
  int tid = threadIdx.x;
  bcnt[tid] = 0; bfill[tid] = 0;
  __syncthreads();
  int cb = blockIdx.x * CHUNK;
  int ce = min(cb + CHUNK, e);
  for (int i = cb + tid; i < ce; i += 256)
    atomicAdd(&bcnt[dst[i] >> BSH], 1);
  __syncthreads();
  if (bcnt[tid] > 0) gbase[tid] = atomicAdd(&cursor[tid], bcnt[tid]);
  __syncthreads();
  for (int i = cb + tid; i < ce; i += 256) {
    int d = dst[i];
    int b = d >> BSH;
    int slot = atomicAdd(&bfill[b], 1);
    size_t pos = (size_t)b * PCAP + gbase[b] + slot;
    rec_stage[pos] =
        ((unsigned long long)__float_as_uint(ea[i]) << 32) | (unsigned int)src[i];
    dloc_stage[pos] = (unsigned short)(d & (BSZ - 1));
  }
}

__global__ __launch_bounds__(256) void scanb_kernel(
    const int* __restrict__ cursor, int* __restrict__ bbase,
    int* __restrict__ rowptr_n, int nbk)
{
  int t = threadIdx.x;
  int v = (t < nbk) ? cursor[t] : 0;
  int incl = v;
#pragma unroll
  for (int off = 1; off < 64; off <<= 1) {
    int tv = __shfl_up(incl, off);
    if ((t & 63) >= off) incl += tv;
  }
  __shared__ int ws[4];
  if ((t & 63) == 63) ws[t >> 6] = incl;
  __syncthreads();
  int wb = 0;
  int w = t >> 6;
#pragma unroll
  for (int j = 0; j < 4; j++) if (j < w) wb += ws[j];
  int excl = incl - v + wb;
  if (t < nbk) bbase[t] = excl;
  if (t == 255) *rowptr_n = excl;
}

__global__ __launch_bounds__(256) void place_kernel(
    const int* __restrict__ cursor, const int* __restrict__ bbase,
    const unsigned long long* __restrict__ rec_stage,
    const unsigned short* __restrict__ dloc_stage,
    unsigned long long* __restrict__ edges, int* __restrict__ rowptr, int n)
{
  extern __shared__ char smem[];
  unsigned long long* sbuf = (unsigned long long*)smem;
  int* hist = (int*)(smem + (size_t)PCAP * 8);
  int* lcnt = hist + 256;
  __shared__ int ws[4];
  int b = blockIdx.x;
  int t = threadIdx.x;
  int lo = b * BSZ;
  int hi = min(lo + BSZ, n);
  int cnt  = cursor[b];
  int base = bbase[b];
  size_t bofs = (size_t)b * PCAP;
  hist[t] = 0;
  __syncthreads();
  for (int i = t; i < cnt; i += 256)
    atomicAdd(&hist[dloc_stage[bofs + i]], 1);
  __syncthreads();
  int v = hist[t];
  int incl = v;
#pragma unroll
  for (int off = 1; off < 64; off <<= 1) {
    int tv = __shfl_up(incl, off);
    if ((t & 63) >= off) incl += tv;
  }
  if ((t & 63) == 63) ws[t >> 6] = incl;
  __syncthreads();
  int wb = 0;
  int w = t >> 6;
#pragma unroll
  for (int j = 0; j < 4; j++) if (j < w) wb += ws[j];
  int excl = incl - v + wb;
  if (lo + t < hi) rowptr[lo + t] = base + excl;
  lcnt[t] = excl;
  __syncthreads();
  for (int i = t; i < cnt; i += 256) {
    unsigned long long rec = rec_stage[bofs + i];
    int dl = dloc_stage[bofs + i];
    int slot = atomicAdd(&lcnt[dl], 1);
    sbuf[slot] = rec;
  }
  __syncthreads();
  for (int i = t; i < cnt; i += 256)
    edges[(size_t)base + i] = sbuf[i];
}

// ---------------- weight prep ----------------
// Wt cols: 0..767 layers (q|k|v|skip), 768..831 Wc1, 832..895 Win(pad), 896..907 Wc2.
// Also zeroes cursor (block 0) so no separate memset dispatch is needed.

#define NWCOL 908

__global__ __launch_bounds__(256) void wprep_kernel(
    const float* __restrict__ Wq, const float* __restrict__ Wk,
    const float* __restrict__ Wv, const float* __restrict__ Ws,
    const float* __restrict__ Wc1, const float* __restrict__ Win,
    const float* __restrict__ Wc2,
    const float* __restrict__ bq, const float* __restrict__ bk,
    const float* __restrict__ bv, const float* __restrict__ bs,
    const float* __restrict__ bc1, const float* __restrict__ bin,
    const float* __restrict__ bc2,
    _Float16* __restrict__ Wt, float* __restrict__ biasP, int* __restrict__ cursor)
{
  if (blockIdx.x == 0 && threadIdx.x < NBK_MAX) cursor[threadIdx.x] = 0;
  int idx = blockIdx.x * 256 + threadIdx.x;
  if (idx >= NWCOL * 64) return;
  int col = idx >> 6, k = idx & 63;
  float w, b;
  if (col < 768) {
    int l = col >> 8, rem = col & 255;
    int mat = rem >> 6, c = rem & 63;
    const float* W  = (mat == 0) ? Wq : (mat == 1) ? Wk : (mat == 2) ? Wv : Ws;
    const float* bb = (mat == 0) ? bq : (mat == 1) ? bk : (mat == 2) ? bv : bs;
    w = W[((size_t)l * 64 + k) * 64 + c];
    b = bb[l * 64 + c];
  } else if (col < 832) {
    int c = col - 768;
    w = Wc1[k * 64 + c];
    b = bc1[c];
  } else if (col < 896) {
    int c = col - 832;
    w = (k < IN_F) ? Win[k * 64 + c] : 0.f;
    b = bin[c];
  } else {
    int c = col - 896;
    w = Wc2[k * NC + c];
    b = bc2[c];
  }
  Wt[idx] = (_Float16)w;
  if (k == 0) biasP[col] = b;
}

// ---------------- MFMA GEMM ----------------
// MODE=0: plain fp32 C (+RELU). MODE=1 (layer): q*SCQ/xr -> fp16 qxh, k/v -> kvb.
// MODE=2 (classifier): relu(h@Wc1+bc1) kept in LDS fp16, then @Wc2+bc2 -> out.

template<int NMAT, int MODE, bool RELU>
__global__ __launch_bounds__(256) void gemm_mfma(
    const float* __restrict__ A, int lda, int kin, int M,
    const _Float16* __restrict__ Wt, const float* __restrict__ biasP,
    float* __restrict__ C, int ldc,
    __half* __restrict__ qxh, __half* __restrict__ kvb,
    const _Float16* __restrict__ W2t, const float* __restrict__ b2)
{
  __shared__ __align__(16) _Float16 hsh[64 * 72];
  constexpr int KVSZ = (MODE == 1) ? 64 * 128 : 8;
  __shared__ __align__(16) __half kvsh[KVSZ];
  __shared__ __align__(16) __half qxsh[KVSZ];
  __shared__ __align__(4) _Float16 w2sh[NC * 64];
  __shared__ float b2sh[NC];

  const int tid = threadIdx.x;
  const int wave = tid >> 6, lane = tid & 63;
  const int lrow = lane & 15, quad = lane >> 4;
  const int row0 = blockIdx.x * 64;
  constexpr int WPC = 4 / NMAT;
  const int cg = wave / WPC;
  const int wi = wave % WPC;

  half8 bf[4][2];
  const _Float16* wbase = Wt + (size_t)cg * 64 * 64;
#pragma unroll
  for (int ct = 0; ct < 4; ct++)
#pragma unroll
    for (int ks = 0; ks < 2; ks++)
      bf[ct][ks] = *(const half8*)&wbase[(ct * 16 + lrow) * 64 + ks * 32 + quad * 8];
  float bv_[4];
#pragma unroll
  for (int ct = 0; ct < 4; ct++) bv_[ct] = biasP[cg * 64 + ct * 16 + lrow];

  if (MODE == 2) {
    for (int i = tid; i < NC * 64; i += 256) w2sh[i] = W2t[i];
    if (tid < NC) b2sh[tid] = b2[tid];
  }

  if (kin == 64) {
    int r = tid >> 2, cq = tid & 3;
    int grow = row0 + r;
#pragma unroll
    for (int i = 0; i < 4; i++) {
      int c0 = cq * 16 + i * 4;
      float4v v = {0.f, 0.f, 0.f, 0.f};
      if (grow < M)
        v = __builtin_nontemporal_load((const float4v*)&A[(size_t)grow * lda + c0]);
      half4_t hv;
      hv[0] = (_Float16)v[0]; hv[1] = (_Float16)v[1];
      hv[2] = (_Float16)v[2]; hv[3] = (_Float16)v[3];
      *(half4_t*)&hsh[r * 72 + c0] = hv;
    }
  } else {
    for (int idx = tid; idx < 64 * 64; idx += 256) {
      int r = idx >> 6, c = idx & 63;
      int grow = row0 + r;
      float v = (grow < M && c < kin)
                    ? __builtin_nontemporal_load(&A[(size_t)grow * lda + c]) : 0.f;
      hsh[r * 72 + c] = (_Float16)v;
    }
  }
  __syncthreads();

  float4v acc[NMAT][4];
#pragma unroll
  for (int rt = 0; rt < NMAT; rt++)
#pragma unroll
    for (int ct = 0; ct < 4; ct++) {
      acc[rt][ct][0] = bv_[ct]; acc[rt][ct][1] = bv_[ct];
      acc[rt][ct][2] = bv_[ct]; acc[rt][ct][3] = bv_[ct];
    }

#pragma unroll
  for (int rt = 0; rt < NMAT; rt++) {
    int rbase = (wi * NMAT + rt) * 16;
#pragma unroll
    for (int ks = 0; ks < 2; ks++) {
      half8 af = *(const half8*)&hsh[(rbase + lrow) * 72 + ks * 32 + quad * 8];
#pragma unroll
      for (int ct = 0; ct < 4; ct++)
        acc[rt][ct] = __builtin_amdgcn_mfma_f32_16x16x32_f16(af, bf[ct][ks],
                                                             acc[rt][ct], 0, 0, 0);
    }
  }

  if (MODE == 0) {
#pragma unroll
    for (int rt = 0; rt < NMAT; rt++) {
      int rbase = (wi * NMAT + rt) * 16;
#pragma unroll
      for (int reg = 0; reg < 4; reg++) {
        int row = row0 + rbase + quad * 4 + reg;
        if (row < M) {
#pragma unroll
          for (int ct = 0; ct < 4; ct++) {
            float v = acc[rt][ct][reg];
            if (RELU) v = fmaxf(v, 0.f);
            C[(size_t)row * ldc + cg * 64 + ct * 16 + lrow] = v;
          }
        }
      }
    }
  } else if (MODE == 1) {
    __half* dstsh = (cg == 0 || cg == 3) ? qxsh : kvsh;
    int cofs = (cg == 0 || cg == 1) ? 0 : 64;
    float scale = (cg == 0) ? SCQ : 1.f;
#pragma unroll
    for (int rt = 0; rt < 4; rt++)
#pragma unroll
      for (int reg = 0; reg < 4; reg++) {
        int rloc = rt * 16 + quad * 4 + reg;
#pragma unroll
        for (int ct = 0; ct < 4; ct++)
          dstsh[rloc * 128 + cofs + ct * 16 + lrow] =
              __float2half(acc[rt][ct][reg] * scale);
      }
    __syncthreads();
    for (int idx = tid; idx < 1024; idx += 256) {
      int r = idx >> 4, c4 = idx & 15;
      int grow = row0 + r;
      if (grow < M) {
        uint2 kk = *(const uint2*)&kvsh[r * 128 + c4 * 4];
        uint2 vv = *(const uint2*)&kvsh[r * 128 + 64 + c4 * 4];
        uint4 o; o.x = kk.x; o.y = kk.y; o.z = vv.x; o.w = vv.y;
        *(uint4*)&kvb[(size_t)grow * 128 + c4 * 8] = o;
      }
    }
    for (int idx = tid; idx < 1024; idx += 256) {
      int r = idx >> 4, g8 = idx & 15;
      int grow = row0 + r;
      if (grow < M)
        *(uint4*)&qxh[(size_t)grow * 128 + g8 * 8] =
            *(const uint4*)&qxsh[r * 128 + g8 * 8];
    }
  } else {
    // MODE==2: fused classifier. Stage relu(h1) fp16 into hsh, then @Wc2.
    __syncthreads();   // all MFMA reads of hsh complete
    int rbase = wi * 16;
#pragma unroll
    for (int reg = 0; reg < 4; reg++) {
      int row = rbase + quad * 4 + reg;
#pragma unroll
      for (int ct = 0; ct < 4; ct++)
        hsh[row * 72 + ct * 16 + lrow] = (_Float16)fmaxf(acc[0][ct][reg], 0.f);
    }
    __syncthreads();
    int o = tid * 3;
#pragma unroll
    for (int t = 0; t < 3; t++, o++) {
      int r = o / NC, c = o - (o / NC) * NC;
      float s = b2sh[c];
#pragma unroll
      for (int k2 = 0; k2 < 32; k2++)
        s = FDOT2(*(const half2_t*)&hsh[r * 72 + k2 * 2],
                  *(const half2_t*)&w2sh[c * 64 + k2 * 2], s);
      int grow = row0 + r;
      if (grow < M) C[(size_t)grow * NC + c] = s;
    }
  }
}

// ---------------- fused attention + gate + LayerNorm ----------------
// qxh: [node][128 halfs] = q*SCQ (0:64) | xr (64:128); kvb: [node][16 uint4].
// Streaming inputs (edges, qxh) use nontemporal loads to preserve L2 for kvb.

__global__ __launch_bounds__(256) void attn_post_kernel(
    const int* __restrict__ rowptr, const unsigned long long* __restrict__ edges,
    const __half* __restrict__ qxh, const uint4* __restrict__ kvb,
    const float* __restrict__ wedge, const float* __restrict__ wbeta,
    const float* __restrict__ lng, const float* __restrict__ lnb,
    float* __restrict__ h, int n)
{
  int lane = threadIdx.x & 63;
  int node = blockIdx.x * 4 + (threadIdx.x >> 6);
  if (node >= n) return;
  int grp = lane >> 4;
  int c4 = lane & 15;
  const __half* qrow = qxh + (size_t)node * 128;
  uint2v qu = __builtin_nontemporal_load(&((const uint2v*)qrow)[c4]);
  half2_t qh01 = h2cast(qu[0]), qh23 = h2cast(qu[1]);
  float qf0 = (float)qh01[0], qf1 = (float)qh01[1];
  float qf2 = (float)qh23[0], qf3 = (float)qh23[1];
  float4 we4 = ((const float4*)wedge)[c4];
  float qwe = qf0 * we4.x + qf1 * we4.y + qf2 * we4.z + qf3 * we4.w;
  int s0 = rowptr[node], s1 = rowptr[node + 1];
  float l = 0.f, pa = 0.f;
  float ax = 0.f, ay = 0.f, az = 0.f, aw = 0.f;
  for (int cb = s0; cb < s1; cb += 64) {
    int cnt = min(64, s1 - cb);
    unsigned long long rec64 = 0ull;
    if (lane < cnt) rec64 = __builtin_nontemporal_load(&edges[cb + lane]);
    unsigned int my_src = (unsigned int)(rec64 & 0xffffffffu);
    unsigned int my_ea  = (unsigned int)(rec64 >> 32);
#pragma unroll 4
    for (int j = 0; j * 4 < cnt; j++) {
      int sl = j * 4 + grp;
      bool valid = sl < cnt;
      int srcn   = (int)__shfl(my_src, sl);
      float a    = __uint_as_float(__shfl(my_ea, sl));
      uint4 kv = kvb[(size_t)srcn * 16 + c4];
      float prod = a * qwe;
      prod = FDOT2(qh01, h2cast(kv.x), prod);
      prod = FDOT2(qh23, h2cast(kv.y), prod);
      prod += __shfl_xor(prod, 1);
      prod += __shfl_xor(prod, 2);
      float p = valid ? exp2f(prod) : 0.f;
      half2_t v01 = h2cast(kv.z), v23 = h2cast(kv.w);
      l  += p;
      pa = fmaf(p, a, pa);
      ax = fmaf(p, (float)v01[0], ax);
      ay = fmaf(p, (float)v01[1], ay);
      az = fmaf(p, (float)v23[0], az);
      aw = fmaf(p, (float)v23[1], aw);
    }
  }
  ax += pa * we4.x; ay += pa * we4.y; az += pa * we4.z; aw += pa * we4.w;
  ax += __shfl_xor(ax, 16); ax += __shfl_xor(ax, 32);
  ay += __shfl_xor(ay, 16); ay += __shfl_xor(ay, 32);
  az += __shfl_xor(az, 16); az += __shfl_xor(az, 32);
  aw += __shfl_xor(aw, 16); aw += __shfl_xor(aw, 32);
  l  += __shfl_xor(l, 16);  l  += __shfl_xor(l, 32);
  float inv = 1.f / (l + 1e-16f);
  float ox = ax * inv, oy = ay * inv, oz = az * inv, ow = aw * inv;
  uint2v xu = __builtin_nontemporal_load(&((const uint2v*)(qrow + 64))[c4]);
  half2_t x01 = h2cast(xu[0]), x23 = h2cast(xu[1]);
  float4 xr;
  xr.x = (float)x01[0]; xr.y = (float)x01[1];
  xr.z = (float)x23[0]; xr.w = (float)x23[1];
  float4 hr = ((const float4*)h)[(size_t)node * 16 + c4];
  float4 w1 = ((const float4*)wbeta)[c4];
  float4 w2 = ((const float4*)wbeta)[16 + c4];
  float4 w3 = ((const float4*)wbeta)[32 + c4];
  float sv = ox * w1.x + oy * w1.y + oz * w1.z + ow * w1.w
           + xr.x * w2.x + xr.y * w2.y + xr.z * w2.z + xr.w * w2.w
           + (ox - xr.x) * w3.x + (oy - xr.y) * w3.y
           + (oz - xr.z) * w3.z + (ow - xr.w) * w3.w;
  sv += __shfl_xor(sv, 1); sv += __shfl_xor(sv, 2);
  sv += __shfl_xor(sv, 4); sv += __shfl_xor(sv, 8);
  float beta = 1.f / (1.f + __expf(-sv));
  float zx = beta * xr.x + (1.f - beta) * ox + hr.x;
  float zy = beta * xr.y + (1.f - beta) * oy + hr.y;
  float zz = beta * xr.z + (1.f - beta) * oz + hr.z;
  float zw = beta * xr.w + (1.f - beta) * ow + hr.w;
  float mu = zx + zy + zz + zw;
  mu += __shfl_xor(mu, 1); mu += __shfl_xor(mu, 2);
  mu += __shfl_xor(mu, 4); mu += __shfl_xor(mu, 8);
  mu *= (1.f / 64.f);
  float dx = zx - mu, dy = zy - mu, dz = zz - mu, dw = zw - mu;
  float var = dx * dx + dy * dy + dz * dz + dw * dw;
  var += __shfl_xor(var, 1); var += __shfl_xor(var, 2);
  var += __shfl_xor(var, 4); var += __shfl_xor(var, 8);
  var *= (1.f / 64.f);
  float rstd = rsqrtf(var + LN_EPS);
  float4 g4 = ((const float4*)lng)[c4];
  float4 b4 = ((const float4*)lnb)[c4];
  if (grp == 0) {
    float4 res;
    res.x = dx * rstd * g4.x + b4.x;
    res.y = dy * rstd * g4.y + b4.y;
    res.z = dz * rstd * g4.z + b4.z;
    res.w = dw * rstd * g4.w + b4.w;
    ((float4*)h)[(size_t)node * 16 + c4] = res;
  }
}

// ---------------- launch ----------------

extern "C" void kernel_launch(void* const* d_in, const int* in_sizes, int n_in,
                              void* d_out, int out_size, void* d_ws, size_t ws_size,
                              hipStream_t stream) {
  const float* x     = (const float*)d_in[0];
  const int*   eidx  = (const int*)d_in[1];
  const float* eattr = (const float*)d_in[2];
  const float* Win   = (const float*)d_in[3];
  const float* b_in  = (const float*)d_in[4];
  const float* Wq    = (const float*)d_in[5];
  const float* bq    = (const float*)d_in[6];
  const float* Wk    = (const float*)d_in[7];
  const float* bk    = (const float*)d_in[8];
  const float* Wv    = (const float*)d_in[9];
  const float* bv    = (const float*)d_in[10];
  const float* Wedge = (const float*)d_in[11];
  const float* Wskip = (const float*)d_in[12];
  const float* bskip = (const float*)d_in[13];
  const float* Wbeta = (const float*)d_in[14];
  const float* ln_g  = (const float*)d_in[15];
  const float* ln_b  = (const float*)d_in[16];
  const float* Wc1   = (const float*)d_in[17];
  const float* bc1   = (const float*)d_in[18];
  const float* Wc2   = (const float*)d_in[19];
  const float* bc2   = (const float*)d_in[20];
  float* out = (float*)d_out;

  int n = in_sizes[0] / IN_F;   // 50000
  int e = in_sizes[2];          // 800000
  const int* src = eidx;
  const int* dstp = eidx + e;

  char* ws = (char*)d_ws;
  size_t off = 0;
  auto alloc = [&](size_t bytes) { void* p = ws + off; off += (bytes + 255) & ~(size_t)255; return p; };
  int nbk = (n + BSZ - 1) / BSZ;      // 196 buckets

  int*    rowptr = (int*)alloc((size_t)(n + 1) * 4);
  int*    cursor = (int*)alloc(NBK_MAX * 4);
  int*    bbase  = (int*)alloc(NBK_MAX * 4);
  unsigned long long* rec_stage = (unsigned long long*)alloc((size_t)nbk * PCAP * 8);
  unsigned short*     dloc_stage = (unsigned short*)alloc((size_t)nbk * PCAP * 2);
  unsigned long long* edges = (unsigned long long*)alloc((size_t)e * 8);
  float*  h      = (float*)alloc((size_t)n * HID * 4);
  __half* qxh    = (__half*)alloc((size_t)n * 128 * 2);
  __half* kvb    = (__half*)alloc((size_t)n * 128 * 2);
  _Float16* Wt   = (_Float16*)alloc((size_t)NWCOL * 64 * 2);
  float*  biasP  = (float*)alloc(NWCOL * 4);

  int mtiles = (n + 63) / 64;         // 782

  wprep_kernel<<<(NWCOL * 64 + 255) / 256, 256, 0, stream>>>(
      Wq, Wk, Wv, Wskip, Wc1, Win, Wc2, bq, bk, bv, bskip, bc1, b_in, bc2,
      Wt, biasP, cursor);

  bucket_kernel<<<(e + CHUNK - 1) / CHUNK, 256, 0, stream>>>(
      src, dstp, eattr, cursor, rec_stage, dloc_stage, e);
  scanb_kernel<<<1, 256, 0, stream>>>(cursor, bbase, rowptr + n, nbk);
  size_t psmem = (size_t)PCAP * 8 + 512 * 4;
  place_kernel<<<nbk, 256, psmem, stream>>>(
      cursor, bbase, rec_stage, dloc_stage, edges, rowptr, n);

  // h = x @ Win + b_in   (K padded 50->64)
  gemm_mfma<1, 0, false><<<mtiles, 256, 0, stream>>>(
      x, IN_F, IN_F, n, Wt + (size_t)832 * 64, biasP + 832, h, HID,
      nullptr, nullptr, nullptr, nullptr);

  for (int i = 0; i < 3; i++) {
    gemm_mfma<4, 1, false><<<mtiles, 256, 0, stream>>>(
        h, HID, HID, n, Wt + (size_t)i * 256 * 64, biasP + i * 256,
        nullptr, 0, qxh, kvb, nullptr, nullptr);
    attn_post_kernel<<<(n + 3) / 4, 256, 0, stream>>>(
        rowptr, edges, qxh, (const uint4*)kvb, Wedge + i * HID, Wbeta + i * 3 * HID,
        ln_g + i * HID, ln_b + i * HID, h, n);
  }

  // fused classifier: out = relu(h@Wc1+bc1) @ Wc2 + bc2
  gemm_mfma<1, 2, true><<<mtiles, 256, 0, stream>>>(
      h, HID, HID, n, Wt + (size_t)768 * 64, biasP + 768, out, NC,
      nullptr, nullptr, Wt + (size_t)896 * 64, biasP + 896);
}

// Round 12
// 328.352 us; speedup vs baseline: 1.0862x; 1.0862x over previous
//
#include <hip/hip_runtime.h>
#include <hip/hip_fp16.h>
#include <math.h>

#define IN_F 50
#define HID 64
#define NC 12
#define LN_EPS 1e-5f

// Bucketed CSR build parameters
#define BSH 8                 // bucket = dst >> 8 (256 nodes/bucket)
#define BSZ 256
#define NBK_MAX 256
#define CHUNK 8192
#define PCAP 8192             // per-bucket capacity (mean 4096, +64 sigma)

#define SCQ 0.36067376022224085f   // 0.25 * log2(e)

typedef _Float16 half8 __attribute__((ext_vector_type(8)));
typedef _Float16 half4_t __attribute__((ext_vector_type(4)));
typedef _Float16 half2_t __attribute__((ext_vector_type(2)));
typedef float float4v __attribute__((ext_vector_type(4)));

static __device__ __forceinline__ half2_t h2cast(unsigned int u) {
  return __builtin_bit_cast(half2_t, u);
}
static __device__ __forceinline__ unsigned int h2pack(_Float16 a, _Float16 b) {
  half2_t v; v[0] = a; v[1] = b;
  return __builtin_bit_cast(unsigned int, v);
}

#if __has_builtin(__builtin_amdgcn_fdot2)
#define FDOT2(a, b, c) __builtin_amdgcn_fdot2((a), (b), (c), false)
#else
static __device__ __forceinline__ float FDOT2(half2_t a, half2_t b, float c) {
  return (float)a[0] * (float)b[0] + (float)a[1] * (float)b[1] + c;
}
#endif

// ---------------- CSR construction (bucketed counting sort) ----------------

__global__ __launch_bounds__(256) void bucket_kernel(
    const int* __restrict__ src, const int* __restrict__ dst,
    const float* __restrict__ ea, int* __restrict__ cursor,
    unsigned long long* __restrict__ rec_stage,
    unsigned short* __restrict__ dloc_stage, int e)
{
  __shared__ int bcnt[256];
  __shared__ int gbase[256];
  __shared__ int bfill[256];
  int tid = threadIdx.x;
  bcnt[tid] = 0; bfill[tid] = 0;
  __syncthreads();
  int cb = blockIdx.x * CHUNK;
  int ce = min(cb + CHUNK, e);
  for (int i = cb + tid; i < ce; i += 256)
    atomicAdd(&bcnt[dst[i] >> BSH], 1);
  __syncthreads();
  if (bcnt[tid] > 0) gbase[tid] = atomicAdd(&cursor[tid], bcnt[tid]);
  __syncthreads();
  for (int i = cb + tid; i < ce; i += 256) {
    int d = dst[i];
    int b = d >> BSH;
    int slot = atomicAdd(&bfill[b], 1);
    size_t pos = (size_t)b * PCAP + gbase[b] + slot;
    rec_stage[pos] =
        ((unsigned long long)__float_as_uint(ea[i]) << 32) | (unsigned int)src[i];
    dloc_stage[pos] = (unsigned short)(d & (BSZ - 1));
  }
}

__global__ __launch_bounds__(256) void scanb_kernel(
    const int* __restrict__ cursor, int* __restrict__ bbase,
    int* __restrict__ rowptr_n, int nbk)
{
  int t = threadIdx.x;
  int v = (t < nbk) ? cursor[t] : 0;
  int incl = v;
#pragma unroll
  for (int off = 1; off < 64; off <<= 1) {
    int tv = __shfl_up(incl, off);
    if ((t & 63) >= off) incl += tv;
  }
  __shared__ int ws[4];
  if ((t & 63) == 63) ws[t >> 6] = incl;
  __syncthreads();
  int wb = 0;
  int w = t >> 6;
#pragma unroll
  for (int j = 0; j < 4; j++) if (j < w) wb += ws[j];
  int excl = incl - v + wb;
  if (t < nbk) bbase[t] = excl;
  if (t == 255) *rowptr_n = excl;
}

__global__ __launch_bounds__(256) void place_kernel(
    const int* __restrict__ cursor, const int* __restrict__ bbase,
    const unsigned long long* __restrict__ rec_stage,
    const unsigned short* __restrict__ dloc_stage,
    unsigned long long* __restrict__ edges, int* __restrict__ rowptr, int n)
{
  extern __shared__ char smem[];
  unsigned long long* sbuf = (unsigned long long*)smem;
  int* hist = (int*)(smem + (size_t)PCAP * 8);
  int* lcnt = hist + 256;
  __shared__ int ws[4];
  int b = blockIdx.x;
  int t = threadIdx.x;
  int lo = b * BSZ;
  int hi = min(lo + BSZ, n);
  int cnt  = cursor[b];
  int base = bbase[b];
  size_t bofs = (size_t)b * PCAP;
  hist[t] = 0;
  __syncthreads();
  for (int i = t; i < cnt; i += 256)
    atomicAdd(&hist[dloc_stage[bofs + i]], 1);
  __syncthreads();
  int v = hist[t];
  int incl = v;
#pragma unroll
  for (int off = 1; off < 64; off <<= 1) {
    int tv = __shfl_up(incl, off);
    if ((t & 63) >= off) incl += tv;
  }
  if ((t & 63) == 63) ws[t >> 6] = incl;
  __syncthreads();
  int wb = 0;
  int w = t >> 6;
#pragma unroll
  for (int j = 0; j < 4; j++) if (j < w) wb += ws[j];
  int excl = incl - v + wb;
  if (lo + t < hi) rowptr[lo + t] = base + excl;
  lcnt[t] = excl;
  __syncthreads();
  for (int i = t; i < cnt; i += 256) {
    unsigned long long rec = rec_stage[bofs + i];
    int dl = dloc_stage[bofs + i];
    int slot = atomicAdd(&lcnt[dl], 1);
    sbuf[slot] = rec;
  }
  __syncthreads();
  for (int i = t; i < cnt; i += 256)
    edges[(size_t)base + i] = sbuf[i];
}

// ---------------- weight prep ----------------
// Wt cols: 0..767 layers (q|k|v|skip), 768..831 Wc1, 832..895 Win(pad), 896..907 Wc2.
// Block 0 also zeroes cursor.

#define NWCOL 908

__global__ __launch_bounds__(256) void wprep_kernel(
    const float* __restrict__ Wq, const float* __restrict__ Wk,
    const float* __restrict__ Wv, const float* __restrict__ Ws,
    const float* __restrict__ Wc1, const float* __restrict__ Win,
    const float* __restrict__ Wc2,
    const float* __restrict__ bq, const float* __restrict__ bk,
    const float* __restrict__ bv, const float* __restrict__ bs,
    const float* __restrict__ bc1, const float* __restrict__ bin,
    const float* __restrict__ bc2,
    _Float16* __restrict__ Wt, float* __restrict__ biasP, int* __restrict__ cursor)
{
  if (blockIdx.x == 0 && threadIdx.x < NBK_MAX) cursor[threadIdx.x] = 0;
  int idx = blockIdx.x * 256 + threadIdx.x;
  if (idx >= NWCOL * 64) return;
  int col = idx >> 6, k = idx & 63;
  float w, b;
  if (col < 768) {
    int l = col >> 8, rem = col & 255;
    int mat = rem >> 6, c = rem & 63;
    const float* W  = (mat == 0) ? Wq : (mat == 1) ? Wk : (mat == 2) ? Wv : Ws;
    const float* bb = (mat == 0) ? bq : (mat == 1) ? bk : (mat == 2) ? bv : bs;
    w = W[((size_t)l * 64 + k) * 64 + c];
    b = bb[l * 64 + c];
  } else if (col < 832) {
    int c = col - 768;
    w = Wc1[k * 64 + c];
    b = bc1[c];
  } else if (col < 896) {
    int c = col - 832;
    w = (k < IN_F) ? Win[k * 64 + c] : 0.f;
    b = bin[c];
  } else {
    int c = col - 896;
    w = Wc2[k * NC + c];
    b = bc2[c];
  }
  Wt[idx] = (_Float16)w;
  if (k == 0) biasP[col] = b;
}

// ---------------- MFMA GEMM ----------------
// MODE=1 (layer): q*SCQ/xr -> fp16 qxh, k/v -> kvb. MODE=2: fused classifier
// (relu(h@Wc1+bc1) in LDS fp16, then @Wc2+bc2 -> fp32 out). MODE=3: fp16 C (h).
// AHALF: A is fp16 (h), staged as a pure 16B copy.

template<int NMAT, int MODE, bool RELU, bool AHALF>
__global__ __launch_bounds__(256) void gemm_mfma(
    const void* __restrict__ Av, int lda, int kin, int M,
    const _Float16* __restrict__ Wt, const float* __restrict__ biasP,
    float* __restrict__ C, __half* __restrict__ hout,
    __half* __restrict__ qxh, __half* __restrict__ kvb,
    const _Float16* __restrict__ W2t, const float* __restrict__ b2)
{
  __shared__ __align__(16) _Float16 hsh[64 * 72];
  constexpr int KVSZ = (MODE == 1) ? 64 * 128 : 8;
  __shared__ __align__(16) __half kvsh[KVSZ];
  __shared__ __align__(16) __half qxsh[KVSZ];
  __shared__ __align__(4) _Float16 w2sh[NC * 64];
  __shared__ float b2sh[NC];

  const int tid = threadIdx.x;
  const int wave = tid >> 6, lane = tid & 63;
  const int lrow = lane & 15, quad = lane >> 4;
  const int row0 = blockIdx.x * 64;
  constexpr int WPC = 4 / NMAT;
  const int cg = wave / WPC;
  const int wi = wave % WPC;

  half8 bf[4][2];
  const _Float16* wbase = Wt + (size_t)cg * 64 * 64;
#pragma unroll
  for (int ct = 0; ct < 4; ct++)
#pragma unroll
    for (int ks = 0; ks < 2; ks++)
      bf[ct][ks] = *(const half8*)&wbase[(ct * 16 + lrow) * 64 + ks * 32 + quad * 8];
  float bv_[4];
#pragma unroll
  for (int ct = 0; ct < 4; ct++) bv_[ct] = biasP[cg * 64 + ct * 16 + lrow];

  if (MODE == 2) {
    for (int i = tid; i < NC * 64; i += 256) w2sh[i] = W2t[i];
    if (tid < NC) b2sh[tid] = b2[tid];
  }

  if (AHALF) {
    const __half* Ah = (const __half*)Av;
    // 64 rows x 128 B; 512 16B-chunks over 256 threads
#pragma unroll
    for (int cc = 0; cc < 2; cc++) {
      int c = tid + cc * 256;
      int r = c >> 3, o = (c & 7) * 8;
      int grow = row0 + r;
      half8 v = {};
      if (grow < M) v = *(const half8*)&Ah[(size_t)grow * 64 + o];
      *(half8*)&hsh[r * 72 + o] = v;
    }
  } else {
    const float* Af = (const float*)Av;
    for (int idx = tid; idx < 64 * 64; idx += 256) {
      int r = idx >> 6, c = idx & 63;
      int grow = row0 + r;
      float v = (grow < M && c < kin) ? Af[(size_t)grow * lda + c] : 0.f;
      hsh[r * 72 + c] = (_Float16)v;
    }
  }
  __syncthreads();

  float4v acc[NMAT][4];
#pragma unroll
  for (int rt = 0; rt < NMAT; rt++)
#pragma unroll
    for (int ct = 0; ct < 4; ct++) {
      acc[rt][ct][0] = bv_[ct]; acc[rt][ct][1] = bv_[ct];
      acc[rt][ct][2] = bv_[ct]; acc[rt][ct][3] = bv_[ct];
    }

#pragma unroll
  for (int rt = 0; rt < NMAT; rt++) {
    int rbase = (wi * NMAT + rt) * 16;
#pragma unroll
    for (int ks = 0; ks < 2; ks++) {
      half8 af = *(const half8*)&hsh[(rbase + lrow) * 72 + ks * 32 + quad * 8];
#pragma unroll
      for (int ct = 0; ct < 4; ct++)
        acc[rt][ct] = __builtin_amdgcn_mfma_f32_16x16x32_f16(af, bf[ct][ks],
                                                             acc[rt][ct], 0, 0, 0);
    }
  }

  if (MODE == 3) {
    // fp16 h output
#pragma unroll
    for (int rt = 0; rt < NMAT; rt++) {
      int rbase = (wi * NMAT + rt) * 16;
#pragma unroll
      for (int reg = 0; reg < 4; reg++) {
        int row = row0 + rbase + quad * 4 + reg;
        if (row < M) {
#pragma unroll
          for (int ct = 0; ct < 4; ct++) {
            float v = acc[rt][ct][reg];
            if (RELU) v = fmaxf(v, 0.f);
            hout[(size_t)row * 64 + ct * 16 + lrow] = __float2half(v);
          }
        }
      }
    }
  } else if (MODE == 1) {
    __half* dstsh = (cg == 0 || cg == 3) ? qxsh : kvsh;
    int cofs = (cg == 0 || cg == 1) ? 0 : 64;
    float scale = (cg == 0) ? SCQ : 1.f;
#pragma unroll
    for (int rt = 0; rt < 4; rt++)
#pragma unroll
      for (int reg = 0; reg < 4; reg++) {
        int rloc = rt * 16 + quad * 4 + reg;
#pragma unroll
        for (int ct = 0; ct < 4; ct++)
          dstsh[rloc * 128 + cofs + ct * 16 + lrow] =
              __float2half(acc[rt][ct][reg] * scale);
      }
    __syncthreads();
    for (int idx = tid; idx < 1024; idx += 256) {
      int r = idx >> 4, c4 = idx & 15;
      int grow = row0 + r;
      if (grow < M) {
        uint2 kk = *(const uint2*)&kvsh[r * 128 + c4 * 4];
        uint2 vv = *(const uint2*)&kvsh[r * 128 + 64 + c4 * 4];
        uint4 o; o.x = kk.x; o.y = kk.y; o.z = vv.x; o.w = vv.y;
        *(uint4*)&kvb[(size_t)grow * 128 + c4 * 8] = o;
      }
    }
    for (int idx = tid; idx < 1024; idx += 256) {
      int r = idx >> 4, g8 = idx & 15;
      int grow = row0 + r;
      if (grow < M)
        *(uint4*)&qxh[(size_t)grow * 128 + g8 * 8] =
            *(const uint4*)&qxsh[r * 128 + g8 * 8];
    }
  } else {
    // MODE==2: fused classifier
    __syncthreads();
    int rbase = wi * 16;
#pragma unroll
    for (int reg = 0; reg < 4; reg++) {
      int row = rbase + quad * 4 + reg;
#pragma unroll
      for (int ct = 0; ct < 4; ct++)
        hsh[row * 72 + ct * 16 + lrow] = (_Float16)fmaxf(acc[0][ct][reg], 0.f);
    }
    __syncthreads();
    int o = tid * 3;
#pragma unroll
    for (int t = 0; t < 3; t++, o++) {
      int r = o / NC, c = o - (o / NC) * NC;
      float s = b2sh[c];
#pragma unroll
      for (int k2 = 0; k2 < 32; k2++)
        s = FDOT2(*(const half2_t*)&hsh[r * 72 + k2 * 2],
                  *(const half2_t*)&w2sh[c * 64 + k2 * 2], s);
      int grow = row0 + r;
      if (grow < M) C[(size_t)grow * NC + c] = s;
    }
  }
}

// ---------------- fused attention + gate + LayerNorm ----------------
// qxh: [node][128 halfs] = q*SCQ | xr; kvb: [node][16 uint4]; h: fp16 [node][64].

__global__ __launch_bounds__(256) void attn_post_kernel(
    const int* __restrict__ rowptr, const unsigned long long* __restrict__ edges,
    const __half* __restrict__ qxh, const uint4* __restrict__ kvb,
    const float* __restrict__ wedge, const float* __restrict__ wbeta,
    const float* __restrict__ lng, const float* __restrict__ lnb,
    __half* __restrict__ h, int n)
{
  int lane = threadIdx.x & 63;
  int node = blockIdx.x * 4 + (threadIdx.x >> 6);
  if (node >= n) return;
  int grp = lane >> 4;
  int c4 = lane & 15;
  const __half* qrow = qxh + (size_t)node * 128;
  uint2 qu = ((const uint2*)qrow)[c4];
  half2_t qh01 = h2cast(qu.x), qh23 = h2cast(qu.y);
  float qf0 = (float)qh01[0], qf1 = (float)qh01[1];
  float qf2 = (float)qh23[0], qf3 = (float)qh23[1];
  float4 we4 = ((const float4*)wedge)[c4];
  float qwe = qf0 * we4.x + qf1 * we4.y + qf2 * we4.z + qf3 * we4.w;
  int s0 = rowptr[node], s1 = rowptr[node + 1];
  float l = 0.f, pa = 0.f;
  float ax = 0.f, ay = 0.f, az = 0.f, aw = 0.f;
  for (int cb = s0; cb < s1; cb += 64) {
    int cnt = min(64, s1 - cb);
    unsigned long long rec64 = (lane < cnt) ? edges[cb + lane] : 0ull;
    unsigned int my_src = (unsigned int)(rec64 & 0xffffffffu);
    unsigned int my_ea  = (unsigned int)(rec64 >> 32);
#pragma unroll 2
    for (int j = 0; j * 4 < cnt; j++) {
      int sl = j * 4 + grp;
      bool valid = sl < cnt;
      int srcn   = (int)__shfl(my_src, sl);
      float a    = __uint_as_float(__shfl(my_ea, sl));
      uint4 kv = kvb[(size_t)srcn * 16 + c4];
      float prod = a * qwe;
      prod = FDOT2(qh01, h2cast(kv.x), prod);
      prod = FDOT2(qh23, h2cast(kv.y), prod);
      prod += __shfl_xor(prod, 1);
      prod += __shfl_xor(prod, 2);
      float p = valid ? exp2f(prod) : 0.f;
      half2_t v01 = h2cast(kv.z), v23 = h2cast(kv.w);
      l  += p;
      pa = fmaf(p, a, pa);
      ax = fmaf(p, (float)v01[0], ax);
      ay = fmaf(p, (float)v01[1], ay);
      az = fmaf(p, (float)v23[0], az);
      aw = fmaf(p, (float)v23[1], aw);
    }
  }
  ax += pa * we4.x; ay += pa * we4.y; az += pa * we4.z; aw += pa * we4.w;
  ax += __shfl_xor(ax, 16); ax += __shfl_xor(ax, 32);
  ay += __shfl_xor(ay, 16); ay += __shfl_xor(ay, 32);
  az += __shfl_xor(az, 16); az += __shfl_xor(az, 32);
  aw += __shfl_xor(aw, 16); aw += __shfl_xor(aw, 32);
  l  += __shfl_xor(l, 16);  l  += __shfl_xor(l, 32);
  float inv = 1.f / (l + 1e-16f);
  float ox = ax * inv, oy = ay * inv, oz = az * inv, ow = aw * inv;
  uint2 xu = ((const uint2*)(qrow + 64))[c4];
  half2_t x01 = h2cast(xu.x), x23 = h2cast(xu.y);
  float4 xr;
  xr.x = (float)x01[0]; xr.y = (float)x01[1];
  xr.z = (float)x23[0]; xr.w = (float)x23[1];
  __half* hrow = h + (size_t)node * 64;
  uint2 hu = ((const uint2*)hrow)[c4];
  half2_t h01 = h2cast(hu.x), h23 = h2cast(hu.y);
  float4 hr;
  hr.x = (float)h01[0]; hr.y = (float)h01[1];
  hr.z = (float)h23[0]; hr.w = (float)h23[1];
  float4 w1 = ((const float4*)wbeta)[c4];
  float4 w2 = ((const float4*)wbeta)[16 + c4];
  float4 w3 = ((const float4*)wbeta)[32 + c4];
  float sv = ox * w1.x + oy * w1.y + oz * w1.z + ow * w1.w
           + xr.x * w2.x + xr.y * w2.y + xr.z * w2.z + xr.w * w2.w
           + (ox - xr.x) * w3.x + (oy - xr.y) * w3.y
           + (oz - xr.z) * w3.z + (ow - xr.w) * w3.w;
  sv += __shfl_xor(sv, 1); sv += __shfl_xor(sv, 2);
  sv += __shfl_xor(sv, 4); sv += __shfl_xor(sv, 8);
  float beta = 1.f / (1.f + __expf(-sv));
  float zx = beta * xr.x + (1.f - beta) * ox + hr.x;
  float zy = beta * xr.y + (1.f - beta) * oy + hr.y;
  float zz = beta * xr.z + (1.f - beta) * oz + hr.z;
  float zw = beta * xr.w + (1.f - beta) * ow + hr.w;
  float mu = zx + zy + zz + zw;
  mu += __shfl_xor(mu, 1); mu += __shfl_xor(mu, 2);
  mu += __shfl_xor(mu, 4); mu += __shfl_xor(mu, 8);
  mu *= (1.f / 64.f);
  float dx = zx - mu, dy = zy - mu, dz = zz - mu, dw = zw - mu;
  float var = dx * dx + dy * dy + dz * dz + dw * dw;
  var += __shfl_xor(var, 1); var += __shfl_xor(var, 2);
  var += __shfl_xor(var, 4); var += __shfl_xor(var, 8);
  var *= (1.f / 64.f);
  float rstd = rsqrtf(var + LN_EPS);
  float4 g4 = ((const float4*)lng)[c4];
  float4 b4 = ((const float4*)lnb)[c4];
  if (grp == 0) {
    uint2 res;
    res.x = h2pack((_Float16)(dx * rstd * g4.x + b4.x),
                   (_Float16)(dy * rstd * g4.y + b4.y));
    res.y = h2pack((_Float16)(dz * rstd * g4.z + b4.z),
                   (_Float16)(dw * rstd * g4.w + b4.w));
    ((uint2*)hrow)[c4] = res;
  }
}

// ---------------- launch ----------------

extern "C" void kernel_launch(void* const* d_in, const int* in_sizes, int n_in,
                              void* d_out, int out_size, void* d_ws, size_t ws_size,
                              hipStream_t stream) {
  const float* x     = (const float*)d_in[0];
  const int*   eidx  = (const int*)d_in[1];
  const float* eattr = (const float*)d_in[2];
  const float* Win   = (const float*)d_in[3];
  const float* b_in  = (const float*)d_in[4];
  const float* Wq    = (const float*)d_in[5];
  const float* bq    = (const float*)d_in[6];
  const float* Wk    = (const float*)d_in[7];
  const float* bk    = (const float*)d_in[8];
  const float* Wv    = (const float*)d_in[9];
  const float* bv    = (const float*)d_in[10];
  const float* Wedge = (const float*)d_in[11];
  const float* Wskip = (const float*)d_in[12];
  const float* bskip = (const float*)d_in[13];
  const float* Wbeta = (const float*)d_in[14];
  const float* ln_g  = (const float*)d_in[15];
  const float* ln_b  = (const float*)d_in[16];
  const float* Wc1   = (const float*)d_in[17];
  const float* bc1   = (const float*)d_in[18];
  const float* Wc2   = (const float*)d_in[19];
  const float* bc2   = (const float*)d_in[20];
  float* out = (float*)d_out;

  int n = in_sizes[0] / IN_F;   // 50000
  int e = in_sizes[2];          // 800000
  const int* src = eidx;
  const int* dstp = eidx + e;

  char* ws = (char*)d_ws;
  size_t off = 0;
  auto alloc = [&](size_t bytes) { void* p = ws + off; off += (bytes + 255) & ~(size_t)255; return p; };
  int nbk = (n + BSZ - 1) / BSZ;      // 196 buckets

  int*    rowptr = (int*)alloc((size_t)(n + 1) * 4);
  int*    cursor = (int*)alloc(NBK_MAX * 4);
  int*    bbase  = (int*)alloc(NBK_MAX * 4);
  unsigned long long* rec_stage = (unsigned long long*)alloc((size_t)nbk * PCAP * 8);
  unsigned short*     dloc_stage = (unsigned short*)alloc((size_t)nbk * PCAP * 2);
  unsigned long long* edges = (unsigned long long*)alloc((size_t)e * 8);
  __half* h      = (__half*)alloc((size_t)n * HID * 2);
  __half* qxh    = (__half*)alloc((size_t)n * 128 * 2);
  __half* kvb    = (__half*)alloc((size_t)n * 128 * 2);
  _Float16* Wt   = (_Float16*)alloc((size_t)NWCOL * 64 * 2);
  float*  biasP  = (float*)alloc(NWCOL * 4);

  int mtiles = (n + 63) / 64;         // 782

  wprep_kernel<<<(NWCOL * 64 + 255) / 256, 256, 0, stream>>>(
      Wq, Wk, Wv, Wskip, Wc1, Win, Wc2, bq, bk, bv, bskip, bc1, b_in, bc2,
      Wt, biasP, cursor);

  bucket_kernel<<<(e + CHUNK - 1) / CHUNK, 256, 0, stream>>>(
      src, dstp, eattr, cursor, rec_stage, dloc_stage, e);
  scanb_kernel<<<1, 256, 0, stream>>>(cursor, bbase, rowptr + n, nbk);
  size_t psmem = (size_t)PCAP * 8 + 512 * 4;
  place_kernel<<<nbk, 256, psmem, stream>>>(
      cursor, bbase, rec_stage, dloc_stage, edges, rowptr, n);

  // h(fp16) = x @ Win + b_in   (K padded 50->64)
  gemm_mfma<1, 3, false, false><<<mtiles, 256, 0, stream>>>(
      x, IN_F, IN_F, n, Wt + (size_t)832 * 64, biasP + 832,
      nullptr, h, nullptr, nullptr, nullptr, nullptr);

  for (int i = 0; i < 3; i++) {
    gemm_mfma<4, 1, false, true><<<mtiles, 256, 0, stream>>>(
        h, HID, HID, n, Wt + (size_t)i * 256 * 64, biasP + i * 256,
        nullptr, nullptr, qxh, kvb, nullptr, nullptr);
    attn_post_kernel<<<(n + 3) / 4, 256, 0, stream>>>(
        rowptr, edges, qxh, (const uint4*)kvb, Wedge + i * HID, Wbeta + i * 3 * HID,
        ln_g + i * HID, ln_b + i * HID, h, n);
  }

  // fused classifier: out = relu(h@Wc1+bc1) @ Wc2 + bc2
  gemm_mfma<1, 2, true, true><<<mtiles, 256, 0, stream>>>(
      h, HID, HID, n, Wt + (size_t)768 * 64, biasP + 768, out, nullptr,
      nullptr, nullptr, Wt + (size_t)896 * 64, biasP + 896);
}

// Round 13
// 327.723 us; speedup vs baseline: 1.0882x; 1.0019x over previous
//
#include <hip/hip_runtime.h>
#include <hip/hip_fp16.h>
#include <math.h>

#define IN_F 50
#define HID 64
#define NC 12
#define LN_EPS 1e-5f

// Bucketed CSR build parameters
#define BSH 8                 // bucket = dst >> 8 (256 nodes/bucket)
#define BSZ 256
#define NBK_MAX 256
#define CHUNK 8192
#define PCAP 8192             // per-bucket capacity (mean 4096, +64 sigma)

#define SCQ 0.36067376022224085f   // 0.25 * log2(e)

typedef _Float16 half8 __attribute__((ext_vector_type(8)));
typedef _Float16 half4_t __attribute__((ext_vector_type(4)));
typedef _Float16 half2_t __attribute__((ext_vector_type(2)));
typedef float float4v __attribute__((ext_vector_type(4)));

static __device__ __forceinline__ half2_t h2cast(unsigned int u) {
  return __builtin_bit_cast(half2_t, u);
}
static __device__ __forceinline__ unsigned int h2pack(_Float16 a, _Float16 b) {
  half2_t v; v[0] = a; v[1] = b;
  return __builtin_bit_cast(unsigned int, v);
}

#if __has_builtin(__builtin_amdgcn_fdot2)
#define FDOT2(a, b, c) __builtin_amdgcn_fdot2((a), (b), (c), false)
#else
static __device__ __forceinline__ float FDOT2(half2_t a, half2_t b, float c) {
  return (float)a[0] * (float)b[0] + (float)a[1] * (float)b[1] + c;
}
#endif

// ---------------- CSR construction (bucketed counting sort) ----------------

__global__ __launch_bounds__(256) void bucket_kernel(
    const int* __restrict__ src, const int* __restrict__ dst,
    const float* __restrict__ ea, int* __restrict__ cursor,
    unsigned long long* __restrict__ rec_stage,
    unsigned short* __restrict__ dloc_stage, int e)
{
  __shared__ int bcnt[256];
  __shared__ int gbase[256];
  __shared__ int bfill[256];
  int tid = threadIdx.x;
  bcnt[tid] = 0; bfill[tid] = 0;
  __syncthreads();
  int cb = blockIdx.x * CHUNK;
  int ce = min(cb + CHUNK, e);
  for (int i = cb + tid; i < ce; i += 256)
    atomicAdd(&bcnt[dst[i] >> BSH], 1);
  __syncthreads();
  if (bcnt[tid] > 0) gbase[tid] = atomicAdd(&cursor[tid], bcnt[tid]);
  __syncthreads();
  for (int i = cb + tid; i < ce; i += 256) {
    int d = dst[i];
    int b = d >> BSH;
    int slot = atomicAdd(&bfill[b], 1);
    size_t pos = (size_t)b * PCAP + gbase[b] + slot;
    rec_stage[pos] =
        ((unsigned long long)__float_as_uint(ea[i]) << 32) | (unsigned int)src[i];
    dloc_stage[pos] = (unsigned short)(d & (BSZ - 1));
  }
}

// Phase C: per-bucket exact CSR placement. Each block redundantly scans the
// bucket counts for its own base (196 ints - trivial); block 0 writes rowptr[n].
__global__ __launch_bounds__(256) void place_kernel(
    const int* __restrict__ cursor,
    const unsigned long long* __restrict__ rec_stage,
    const unsigned short* __restrict__ dloc_stage,
    unsigned long long* __restrict__ edges, int* __restrict__ rowptr,
    int n, int nbk)
{
  extern __shared__ char smem[];
  unsigned long long* sbuf = (unsigned long long*)smem;       // PCAP*8
  int* hist  = (int*)(smem + (size_t)PCAP * 8);               // 256
  int* lcnt  = hist + 256;                                    // 256
  int* sexcl = lcnt + 256;                                    // 256
  __shared__ int ws[4];
  __shared__ int wst[4];
  int b = blockIdx.x;
  int t = threadIdx.x;
  // ---- bucket-base scan (replaces scanb kernel) ----
  int cv = (t < nbk) ? cursor[t] : 0;
  int bincl = cv;
#pragma unroll
  for (int off = 1; off < 64; off <<= 1) {
    int tv = __shfl_up(bincl, off);
    if ((t & 63) >= off) bincl += tv;
  }
  if ((t & 63) == 63) wst[t >> 6] = bincl;
  hist[t] = 0;
  __syncthreads();
  int bwb = 0;
  int bw = t >> 6;
#pragma unroll
  for (int j = 0; j < 4; j++) if (j < bw) bwb += wst[j];
  sexcl[t] = bincl - cv + bwb;
  if (b == 0 && t == 255) rowptr[n] = bincl + bwb;   // grand total
  __syncthreads();
  int base = sexcl[b];
  int cnt  = cursor[b];
  int lo = b * BSZ;
  int hi = min(lo + BSZ, n);
  size_t bofs = (size_t)b * PCAP;
  // ---- per-node histogram + scan ----
  for (int i = t; i < cnt; i += 256)
    atomicAdd(&hist[dloc_stage[bofs + i]], 1);
  __syncthreads();
  int v = hist[t];
  int incl = v;
#pragma unroll
  for (int off = 1; off < 64; off <<= 1) {
    int tv = __shfl_up(incl, off);
    if ((t & 63) >= off) incl += tv;
  }
  if ((t & 63) == 63) ws[t >> 6] = incl;
  __syncthreads();
  int wb = 0;
  int w = t >> 6;
#pragma unroll
  for (int j = 0; j < 4; j++) if (j < w) wb += ws[j];
  int excl = incl - v + wb;
  if (lo + t < hi) rowptr[lo + t] = base + excl;
  lcnt[t] = excl;
  __syncthreads();
  for (int i = t; i < cnt; i += 256) {
    unsigned long long rec = rec_stage[bofs + i];
    int dl = dloc_stage[bofs + i];
    int slot = atomicAdd(&lcnt[dl], 1);
    sbuf[slot] = rec;
  }
  __syncthreads();
  for (int i = t; i < cnt; i += 256)
    edges[(size_t)base + i] = sbuf[i];
}

// ---------------- weight prep ----------------
// Wt cols: 0..767 layers (q|k|v|skip), 768..831 Wc1, 832..895 Win(pad), 896..907 Wc2.
// Block 0 also zeroes cursor.

#define NWCOL 908

__global__ __launch_bounds__(256) void wprep_kernel(
    const float* __restrict__ Wq, const float* __restrict__ Wk,
    const float* __restrict__ Wv, const float* __restrict__ Ws,
    const float* __restrict__ Wc1, const float* __restrict__ Win,
    const float* __restrict__ Wc2,
    const float* __restrict__ bq, const float* __restrict__ bk,
    const float* __restrict__ bv, const float* __restrict__ bs,
    const float* __restrict__ bc1, const float* __restrict__ bin,
    const float* __restrict__ bc2,
    _Float16* __restrict__ Wt, float* __restrict__ biasP, int* __restrict__ cursor)
{
  if (blockIdx.x == 0 && threadIdx.x < NBK_MAX) cursor[threadIdx.x] = 0;
  int idx = blockIdx.x * 256 + threadIdx.x;
  if (idx >= NWCOL * 64) return;
  int col = idx >> 6, k = idx & 63;
  float w, b;
  if (col < 768) {
    int l = col >> 8, rem = col & 255;
    int mat = rem >> 6, c = rem & 63;
    const float* W  = (mat == 0) ? Wq : (mat == 1) ? Wk : (mat == 2) ? Wv : Ws;
    const float* bb = (mat == 0) ? bq : (mat == 1) ? bk : (mat == 2) ? bv : bs;
    w = W[((size_t)l * 64 + k) * 64 + c];
    b = bb[l * 64 + c];
  } else if (col < 832) {
    int c = col - 768;
    w = Wc1[k * 64 + c];
    b = bc1[c];
  } else if (col < 896) {
    int c = col - 832;
    w = (k < IN_F) ? Win[k * 64 + c] : 0.f;
    b = bin[c];
  } else {
    int c = col - 896;
    w = Wc2[k * NC + c];
    b = bc2[c];
  }
  Wt[idx] = (_Float16)w;
  if (k == 0) biasP[col] = b;
}

// ---------------- MFMA GEMM ----------------
// MODE=1 (layer): q*SCQ/xr -> fp16 qxh, k/v -> kvb. MODE=2: fused classifier.
// AHALF: A is fp16 h (16B-copy staging). INGEMM: A is fp32 x; a pre-phase
// computes h = x@Win+b_in in-block (band-local hsh overwrite, no barrier
// hazard: each wave reads/writes only its own 16-row band), writes h to
// global, then the 4-matrix layer pass runs from LDS.

template<int NMAT, int MODE, bool RELU, bool AHALF, bool INGEMM>
__global__ __launch_bounds__(256) void gemm_mfma(
    const void* __restrict__ Av, int lda, int kin, int M,
    const _Float16* __restrict__ Wt, const float* __restrict__ biasP,
    float* __restrict__ C, __half* __restrict__ hout,
    __half* __restrict__ qxh, __half* __restrict__ kvb,
    const _Float16* __restrict__ W2t, const float* __restrict__ b2)
{
  __shared__ __align__(16) _Float16 hsh[64 * 72];
  constexpr int KVSZ = (MODE == 1) ? 64 * 128 : 8;
  __shared__ __align__(16) __half kvsh[KVSZ];
  __shared__ __align__(16) __half qxsh[KVSZ];
  __shared__ __align__(4) _Float16 w2sh[NC * 64];
  __shared__ float b2sh[NC];

  const int tid = threadIdx.x;
  const int wave = tid >> 6, lane = tid & 63;
  const int lrow = lane & 15, quad = lane >> 4;
  const int row0 = blockIdx.x * 64;
  constexpr int WPC = 4 / NMAT;
  const int cg = wave / WPC;
  const int wi = wave % WPC;

  half8 bf[4][2];
  const _Float16* wbase = Wt + (size_t)cg * 64 * 64;
#pragma unroll
  for (int ct = 0; ct < 4; ct++)
#pragma unroll
    for (int ks = 0; ks < 2; ks++)
      bf[ct][ks] = *(const half8*)&wbase[(ct * 16 + lrow) * 64 + ks * 32 + quad * 8];
  float bv_[4];
#pragma unroll
  for (int ct = 0; ct < 4; ct++) bv_[ct] = biasP[cg * 64 + ct * 16 + lrow];

  if (MODE == 2) {
    for (int i = tid; i < NC * 64; i += 256) w2sh[i] = W2t[i];
    if (tid < NC) b2sh[tid] = b2[tid];
  }

  if (AHALF) {
    const __half* Ah = (const __half*)Av;
#pragma unroll
    for (int cc = 0; cc < 2; cc++) {
      int c = tid + cc * 256;
      int r = c >> 3, o = (c & 7) * 8;
      int grow = row0 + r;
      half8 v = {};
      if (grow < M) v = *(const half8*)&Ah[(size_t)grow * 64 + o];
      *(half8*)&hsh[r * 72 + o] = v;
    }
  } else {
    const float* Af = (const float*)Av;
    for (int idx = tid; idx < 64 * 64; idx += 256) {
      int r = idx >> 6, c = idx & 63;
      int grow = row0 + r;
      float v = (grow < M && c < kin) ? Af[(size_t)grow * lda + c] : 0.f;
      hsh[r * 72 + c] = (_Float16)v;
    }
  }
  __syncthreads();

  if constexpr (INGEMM) {
    // pre-phase: h = x @ Win + b_in; wave w owns rows [w*16, w*16+16)
    half8 bfi[4][2];
#pragma unroll
    for (int ct = 0; ct < 4; ct++)
#pragma unroll
      for (int ks = 0; ks < 2; ks++)
        bfi[ct][ks] =
            *(const half8*)&W2t[(ct * 16 + lrow) * 64 + ks * 32 + quad * 8];
    float4v hacc[4];
#pragma unroll
    for (int ct = 0; ct < 4; ct++) {
      float bb = b2[ct * 16 + lrow];
      hacc[ct][0] = bb; hacc[ct][1] = bb; hacc[ct][2] = bb; hacc[ct][3] = bb;
    }
    int rbase = wave * 16;
#pragma unroll
    for (int ks = 0; ks < 2; ks++) {
      half8 af = *(const half8*)&hsh[(rbase + lrow) * 72 + ks * 32 + quad * 8];
#pragma unroll
      for (int ct = 0; ct < 4; ct++)
        hacc[ct] = __builtin_amdgcn_mfma_f32_16x16x32_f16(af, bfi[ct][ks],
                                                          hacc[ct], 0, 0, 0);
    }
    // overwrite own band with h (fp16) + write h to global
#pragma unroll
    for (int reg = 0; reg < 4; reg++) {
      int rloc = rbase + quad * 4 + reg;
      int grow = row0 + rloc;
#pragma unroll
      for (int ct = 0; ct < 4; ct++) {
        _Float16 hv = (_Float16)hacc[ct][reg];
        hsh[rloc * 72 + ct * 16 + lrow] = hv;
        if (grow < M)
          hout[(size_t)grow * 64 + ct * 16 + lrow] = __float2half((float)hv);
      }
    }
    __syncthreads();
  }

  float4v acc[NMAT][4];
#pragma unroll
  for (int rt = 0; rt < NMAT; rt++)
#pragma unroll
    for (int ct = 0; ct < 4; ct++) {
      acc[rt][ct][0] = bv_[ct]; acc[rt][ct][1] = bv_[ct];
      acc[rt][ct][2] = bv_[ct]; acc[rt][ct][3] = bv_[ct];
    }

#pragma unroll
  for (int rt = 0; rt < NMAT; rt++) {
    int rbase = (wi * NMAT + rt) * 16;
#pragma unroll
    for (int ks = 0; ks < 2; ks++) {
      half8 af = *(const half8*)&hsh[(rbase + lrow) * 72 + ks * 32 + quad * 8];
#pragma unroll
      for (int ct = 0; ct < 4; ct++)
        acc[rt][ct] = __builtin_amdgcn_mfma_f32_16x16x32_f16(af, bf[ct][ks],
                                                             acc[rt][ct], 0, 0, 0);
    }
  }

  if (MODE == 1) {
    __half* dstsh = (cg == 0 || cg == 3) ? qxsh : kvsh;
    int cofs = (cg == 0 || cg == 1) ? 0 : 64;
    float scale = (cg == 0) ? SCQ : 1.f;
#pragma unroll
    for (int rt = 0; rt < 4; rt++)
#pragma unroll
      for (int reg = 0; reg < 4; reg++) {
        int rloc = rt * 16 + quad * 4 + reg;
#pragma unroll
        for (int ct = 0; ct < 4; ct++)
          dstsh[rloc * 128 + cofs + ct * 16 + lrow] =
              __float2half(acc[rt][ct][reg] * scale);
      }
    __syncthreads();
    for (int idx = tid; idx < 1024; idx += 256) {
      int r = idx >> 4, c4 = idx & 15;
      int grow = row0 + r;
      if (grow < M) {
        uint2 kk = *(const uint2*)&kvsh[r * 128 + c4 * 4];
        uint2 vv = *(const uint2*)&kvsh[r * 128 + 64 + c4 * 4];
        uint4 o; o.x = kk.x; o.y = kk.y; o.z = vv.x; o.w = vv.y;
        *(uint4*)&kvb[(size_t)grow * 128 + c4 * 8] = o;
      }
    }
    for (int idx = tid; idx < 1024; idx += 256) {
      int r = idx >> 4, g8 = idx & 15;
      int grow = row0 + r;
      if (grow < M)
        *(uint4*)&qxh[(size_t)grow * 128 + g8 * 8] =
            *(const uint4*)&qxsh[r * 128 + g8 * 8];
    }
  } else {
    // MODE==2: fused classifier
    __syncthreads();
    int rbase = wi * 16;
#pragma unroll
    for (int reg = 0; reg < 4; reg++) {
      int row = rbase + quad * 4 + reg;
#pragma unroll
      for (int ct = 0; ct < 4; ct++)
        hsh[row * 72 + ct * 16 + lrow] = (_Float16)fmaxf(acc[0][ct][reg], 0.f);
    }
    __syncthreads();
    int o = tid * 3;
#pragma unroll
    for (int t = 0; t < 3; t++, o++) {
      int r = o / NC, c = o - (o / NC) * NC;
      float s = b2sh[c];
#pragma unroll
      for (int k2 = 0; k2 < 32; k2++)
        s = FDOT2(*(const half2_t*)&hsh[r * 72 + k2 * 2],
                  *(const half2_t*)&w2sh[c * 64 + k2 * 2], s);
      int grow = row0 + r;
      if (grow < M) C[(size_t)grow * NC + c] = s;
    }
  }
}

// ---------------- fused attention + gate + LayerNorm ----------------
// qxh: [node][128 halfs] = q*SCQ | xr; kvb: [node][16 uint4]; h: fp16 [node][64].

__global__ __launch_bounds__(256) void attn_post_kernel(
    const int* __restrict__ rowptr, const unsigned long long* __restrict__ edges,
    const __half* __restrict__ qxh, const uint4* __restrict__ kvb,
    const float* __restrict__ wedge, const float* __restrict__ wbeta,
    const float* __restrict__ lng, const float* __restrict__ lnb,
    __half* __restrict__ h, int n)
{
  int lane = threadIdx.x & 63;
  int node = blockIdx.x * 4 + (threadIdx.x >> 6);
  if (node >= n) return;
  int grp = lane >> 4;
  int c4 = lane & 15;
  const __half* qrow = qxh + (size_t)node * 128;
  uint2 qu = ((const uint2*)qrow)[c4];
  half2_t qh01 = h2cast(qu.x), qh23 = h2cast(qu.y);
  float qf0 = (float)qh01[0], qf1 = (float)qh01[1];
  float qf2 = (float)qh23[0], qf3 = (float)qh23[1];
  float4 we4 = ((const float4*)wedge)[c4];
  float qwe = qf0 * we4.x + qf1 * we4.y + qf2 * we4.z + qf3 * we4.w;
  int s0 = rowptr[node], s1 = rowptr[node + 1];
  float l = 0.f, pa = 0.f;
  float ax = 0.f, ay = 0.f, az = 0.f, aw = 0.f;
  for (int cb = s0; cb < s1; cb += 64) {
    int cnt = min(64, s1 - cb);
    unsigned long long rec64 = (lane < cnt) ? edges[cb + lane] : 0ull;
    unsigned int my_src = (unsigned int)(rec64 & 0xffffffffu);
    unsigned int my_ea  = (unsigned int)(rec64 >> 32);
#pragma unroll 2
    for (int j = 0; j * 4 < cnt; j++) {
      int sl = j * 4 + grp;
      bool valid = sl < cnt;
      int srcn   = (int)__shfl(my_src, sl);
      float a    = __uint_as_float(__shfl(my_ea, sl));
      uint4 kv = kvb[(size_t)srcn * 16 + c4];
      float prod = a * qwe;
      prod = FDOT2(qh01, h2cast(kv.x), prod);
      prod = FDOT2(qh23, h2cast(kv.y), prod);
      prod += __shfl_xor(prod, 1);
      prod += __shfl_xor(prod, 2);
      float p = valid ? exp2f(prod) : 0.f;
      half2_t v01 = h2cast(kv.z), v23 = h2cast(kv.w);
      l  += p;
      pa = fmaf(p, a, pa);
      ax = fmaf(p, (float)v01[0], ax);
      ay = fmaf(p, (float)v01[1], ay);
      az = fmaf(p, (float)v23[0], az);
      aw = fmaf(p, (float)v23[1], aw);
    }
  }
  ax += pa * we4.x; ay += pa * we4.y; az += pa * we4.z; aw += pa * we4.w;
  ax += __shfl_xor(ax, 16); ax += __shfl_xor(ax, 32);
  ay += __shfl_xor(ay, 16); ay += __shfl_xor(ay, 32);
  az += __shfl_xor(az, 16); az += __shfl_xor(az, 32);
  aw += __shfl_xor(aw, 16); aw += __shfl_xor(aw, 32);
  l  += __shfl_xor(l, 16);  l  += __shfl_xor(l, 32);
  float inv = 1.f / (l + 1e-16f);
  float ox = ax * inv, oy = ay * inv, oz = az * inv, ow = aw * inv;
  uint2 xu = ((const uint2*)(qrow + 64))[c4];
  half2_t x01 = h2cast(xu.x), x23 = h2cast(xu.y);
  float4 xr;
  xr.x = (float)x01[0]; xr.y = (float)x01[1];
  xr.z = (float)x23[0]; xr.w = (float)x23[1];
  __half* hrow = h + (size_t)node * 64;
  uint2 hu = ((const uint2*)hrow)[c4];
  half2_t h01 = h2cast(hu.x), h23 = h2cast(hu.y);
  float4 hr;
  hr.x = (float)h01[0]; hr.y = (float)h01[1];
  hr.z = (float)h23[0]; hr.w = (float)h23[1];
  float4 w1 = ((const float4*)wbeta)[c4];
  float4 w2 = ((const float4*)wbeta)[16 + c4];
  float4 w3 = ((const float4*)wbeta)[32 + c4];
  float sv = ox * w1.x + oy * w1.y + oz * w1.z + ow * w1.w
           + xr.x * w2.x + xr.y * w2.y + xr.z * w2.z + xr.w * w2.w
           + (ox - xr.x) * w3.x + (oy - xr.y) * w3.y
           + (oz - xr.z) * w3.z + (ow - xr.w) * w3.w;
  sv += __shfl_xor(sv, 1); sv += __shfl_xor(sv, 2);
  sv += __shfl_xor(sv, 4); sv += __shfl_xor(sv, 8);
  float beta = 1.f / (1.f + __expf(-sv));
  float zx = beta * xr.x + (1.f - beta) * ox + hr.x;
  float zy = beta * xr.y + (1.f - beta) * oy + hr.y;
  float zz = beta * xr.z + (1.f - beta) * oz + hr.z;
  float zw = beta * xr.w + (1.f - beta) * ow + hr.w;
  float mu = zx + zy + zz + zw;
  mu += __shfl_xor(mu, 1); mu += __shfl_xor(mu, 2);
  mu += __shfl_xor(mu, 4); mu += __shfl_xor(mu, 8);
  mu *= (1.f / 64.f);
  float dx = zx - mu, dy = zy - mu, dz = zz - mu, dw = zw - mu;
  float var = dx * dx + dy * dy + dz * dz + dw * dw;
  var += __shfl_xor(var, 1); var += __shfl_xor(var, 2);
  var += __shfl_xor(var, 4); var += __shfl_xor(var, 8);
  var *= (1.f / 64.f);
  float rstd = rsqrtf(var + LN_EPS);
  float4 g4 = ((const float4*)lng)[c4];
  float4 b4 = ((const float4*)lnb)[c4];
  if (grp == 0) {
    uint2 res;
    res.x = h2pack((_Float16)(dx * rstd * g4.x + b4.x),
                   (_Float16)(dy * rstd * g4.y + b4.y));
    res.y = h2pack((_Float16)(dz * rstd * g4.z + b4.z),
                   (_Float16)(dw * rstd * g4.w + b4.w));
    ((uint2*)hrow)[c4] = res;
  }
}

// ---------------- launch ----------------

extern "C" void kernel_launch(void* const* d_in, const int* in_sizes, int n_in,
                              void* d_out, int out_size, void* d_ws, size_t ws_size,
                              hipStream_t stream) {
  const float* x     = (const float*)d_in[0];
  const int*   eidx  = (const int*)d_in[1];
  const float* eattr = (const float*)d_in[2];
  const float* Win   = (const float*)d_in[3];
  const float* b_in  = (const float*)d_in[4];
  const float* Wq    = (const float*)d_in[5];
  const float* bq    = (const float*)d_in[6];
  const float* Wk    = (const float*)d_in[7];
  const float* bk    = (const float*)d_in[8];
  const float* Wv    = (const float*)d_in[9];
  const float* bv    = (const float*)d_in[10];
  const float* Wedge = (const float*)d_in[11];
  const float* Wskip = (const float*)d_in[12];
  const float* bskip = (const float*)d_in[13];
  const float* Wbeta = (const float*)d_in[14];
  const float* ln_g  = (const float*)d_in[15];
  const float* ln_b  = (const float*)d_in[16];
  const float* Wc1   = (const float*)d_in[17];
  const float* bc1   = (const float*)d_in[18];
  const float* Wc2   = (const float*)d_in[19];
  const float* bc2   = (const float*)d_in[20];
  float* out = (float*)d_out;

  int n = in_sizes[0] / IN_F;   // 50000
  int e = in_sizes[2];          // 800000
  const int* src = eidx;
  const int* dstp = eidx + e;

  char* ws = (char*)d_ws;
  size_t off = 0;
  auto alloc = [&](size_t bytes) { void* p = ws + off; off += (bytes + 255) & ~(size_t)255; return p; };
  int nbk = (n + BSZ - 1) / BSZ;      // 196 buckets

  int*    rowptr = (int*)alloc((size_t)(n + 1) * 4);
  int*    cursor = (int*)alloc(NBK_MAX * 4);
  unsigned long long* rec_stage = (unsigned long long*)alloc((size_t)nbk * PCAP * 8);
  unsigned short*     dloc_stage = (unsigned short*)alloc((size_t)nbk * PCAP * 2);
  unsigned long long* edges = (unsigned long long*)alloc((size_t)e * 8);
  __half* h      = (__half*)alloc((size_t)n * HID * 2);
  __half* qxh    = (__half*)alloc((size_t)n * 128 * 2);
  __half* kvb    = (__half*)alloc((size_t)n * 128 * 2);
  _Float16* Wt   = (_Float16*)alloc((size_t)NWCOL * 64 * 2);
  float*  biasP  = (float*)alloc(NWCOL * 4);

  int mtiles = (n + 63) / 64;         // 782

  wprep_kernel<<<(NWCOL * 64 + 255) / 256, 256, 0, stream>>>(
      Wq, Wk, Wv, Wskip, Wc1, Win, Wc2, bq, bk, bv, bskip, bc1, b_in, bc2,
      Wt, biasP, cursor);

  bucket_kernel<<<(e + CHUNK - 1) / CHUNK, 256, 0, stream>>>(
      src, dstp, eattr, cursor, rec_stage, dloc_stage, e);
  size_t psmem = (size_t)PCAP * 8 + 768 * 4;
  place_kernel<<<nbk, 256, psmem, stream>>>(
      cursor, rec_stage, dloc_stage, edges, rowptr, n, nbk);

  for (int i = 0; i < 3; i++) {
    if (i == 0) {
      // fused: h = x@Win+b_in, then q/k/v/xr from the in-LDS h tile
      gemm_mfma<4, 1, false, false, true><<<mtiles, 256, 0, stream>>>(
          x, IN_F, IN_F, n, Wt, biasP,
          nullptr, h, qxh, kvb, Wt + (size_t)832 * 64, biasP + 832);
    } else {
      gemm_mfma<4, 1, false, true, false><<<mtiles, 256, 0, stream>>>(
          h, HID, HID, n, Wt + (size_t)i * 256 * 64, biasP + i * 256,
          nullptr, nullptr, qxh, kvb, nullptr, nullptr);
    }
    attn_post_kernel<<<(n + 3) / 4, 256, 0, stream>>>(
        rowptr, edges, qxh, (const uint4*)kvb, Wedge + i * HID, Wbeta + i * 3 * HID,
        ln_g + i * HID, ln_b + i * HID, h, n);
  }

  // fused classifier: out = relu(h@Wc1+bc1) @ Wc2 + bc2
  gemm_mfma<1, 2, true, true, false><<<mtiles, 256, 0, stream>>>(
      h, HID, HID, n, Wt + (size_t)768 * 64, biasP + 768, out, nullptr,
      nullptr, nullptr, Wt + (size_t)896 * 64, biasP + 896);
}